// Round 14
// baseline (483.423 us; speedup 1.0000x reference)
//
#include <hip/hip_runtime.h>
#include <hip/hip_bf16.h>
#include <math.h>

#define N_NODES 50000
#define N_EDGES 800000
#define CLAMP_V 5.0f

typedef short short8 __attribute__((ext_vector_type(8)));
typedef float f32x4  __attribute__((ext_vector_type(4)));

static __device__ inline short f2bf(float x) {
    __hip_bfloat16 h = __float2bfloat16(x);   // RNE
    return __builtin_bit_cast(short, h);
}
static __device__ inline float bf2f(short s) {
    unsigned u = ((unsigned)(unsigned short)s) << 16;
    return __builtin_bit_cast(float, u);
}

// ---------------- Kernel 1: Q/K/V node projections (unchanged, proven) ----------------
__global__ __launch_bounds__(256) void qkv_kernel(
    const float* __restrict__ x,
    const float* __restrict__ WQ, const float* __restrict__ bQ,
    const float* __restrict__ WK, const float* __restrict__ bK,
    const float* __restrict__ WV, const float* __restrict__ bV,
    float* __restrict__ Q, float* __restrict__ K, float* __restrict__ V)
{
    const int t = threadIdx.x;
    const int c = t & 63;
    const int nl = t >> 6;
    const int base = blockIdx.x * 16;

    float accQ[4], accK[4], accV[4];
    int nodes[4];
#pragma unroll
    for (int j = 0; j < 4; ++j) {
        nodes[j] = base + j * 4 + nl;
        accQ[j] = bQ[c]; accK[j] = bK[c]; accV[j] = bV[c];
    }
    for (int k = 0; k < 64; ++k) {
        const float wq = WQ[k * 64 + c];
        const float wk = WK[k * 64 + c];
        const float wv = WV[k * 64 + c];
#pragma unroll
        for (int j = 0; j < 4; ++j) {
            const float xv = x[nodes[j] * 64 + k];
            accQ[j] += xv * wq;
            accK[j] += xv * wk;
            accV[j] += xv * wv;
        }
    }
#pragma unroll
    for (int j = 0; j < 4; ++j) {
        const int n = nodes[j];
        Q[n * 64 + c] = accQ[j];
        K[n * 64 + c] = accK[j];
        V[n * 64 + c] = accV[j];
    }
}

// ---------------- Kernel 2: fused E-GEMM + score + denom + numerators ----------------
// Base: EXACT R10 config (proven 264us edge). Template FOLD_VE:
//  FOLD_VE=1 (ws permitting): accumulate rowV_num[d] += ex*sc (zero shuffles;
//    lane layout of sc already matches rowV) and apply @VeRow in finalize —
//    the reference's own factorization. Deletes the 8-shfl rsum broadcast
//    chain per edge (11 -> 3 DS ops/edge), the prime latency-chain suspect.
//  FOLD_VE=0: R10 path (per-edge VeRow fold), used if ws too small.
template<int FOLD_VE>
__global__ __launch_bounds__(256, 3) void edge_kernel(
    const float* __restrict__ edge_attr,
    const int* __restrict__ src_idx, const int* __restrict__ dst_idx,
    const float* __restrict__ WE, const float* __restrict__ bE,
    const float* __restrict__ Aw,
    const float* __restrict__ Qn, const float* __restrict__ Kn,
    const float* __restrict__ Vn, const float* __restrict__ VeRow,
    float* __restrict__ wE_out, float* __restrict__ denom,
    float* __restrict__ wV_num, float* __restrict__ rowV_num)
{
    // [0,16K)=B_hi  [16K,32K)=B_lo  [32K, +4*2304)=E transpose bufs (padded)
    __shared__ __align__(16) char raw[41984];
    __shared__ float bEs[128];

    short8* Bhi = (short8*)raw;                  // [(ct*2+kh)*64 + lane]
    short8* Blo = (short8*)(raw + 16384);

    const int t = threadIdx.x;
    const int wave = t >> 6;
    const int lane = t & 63;

    // ---- init: bf16 hi/lo B-fragments from global WE
    short* BhiE = (short*)raw;
    short* BloE = (short*)(raw + 16384);
    for (int i = t; i < 8192; i += 256) {
        const int j  = i & 7;
        const int ln = (i >> 3) & 63;
        const int kh = (i >> 9) & 1;
        const int ct = i >> 10;
        const int k   = kh * 32 + ((ln >> 4) << 3) + j;
        const int col = (ct << 4) + (ln & 15);
        const float w = WE[k * 128 + col];
        const short hb = f2bf(w);
        BhiE[i] = hb;
        BloE[i] = f2bf(w - bf2f(hb));
    }
    if (t < 128) bEs[t] = bE[t];
    __syncthreads();

    float* Ebuf_w = (float*)(raw + 32768 + wave * 2304);  // padded layout

    const int h    = lane >> 3;
    const int kk   = lane & 7;
    const int g    = lane >> 4;
    const int c4   = lane & 15;
    const int h16k = (h << 4) + kk;
    const int ewoff = (h16k + (h16k >> 3)) << 2;
    const int eboff = ((h16k + 8) + ((h16k + 8) >> 3)) << 2;

    // loop-invariant weights in registers
    const float aw = Aw[kk * 8 + h];
    float veR[8];
    if (!FOLD_VE) {
#pragma unroll
        for (int dd = 0; dd < 8; ++dd) veR[dd] = VeRow[dd * 64 + lane];
    }

    const int G = (int)gridDim.x;

    // pipeline state
    float4 arC[4], arN[4];
    int seC[16], deC[16], seN[16], deN[16];

    // ---- prologue
    int it = blockIdx.x;
    {
        const int ebase0 = __builtin_amdgcn_readfirstlane(it * 64 + wave * 16);
#pragma unroll
        for (int p = 0; p < 2; ++p) {
            const float* srcp = edge_attr + (size_t)(ebase0 + c4) * 64 + p * 32 + (g << 3);
            arC[2 * p]     = *(const float4*)srcp;
            arC[2 * p + 1] = *(const float4*)(srcp + 4);
        }
#pragma unroll
        for (int r = 0; r < 16; ++r) {
            seC[r] = src_idx[ebase0 + r];
            deC[r] = dst_idx[ebase0 + r];
        }
    }

    for (; it < 12500; it += G) {
        const int ebaseC = __builtin_amdgcn_readfirstlane(it * 64 + wave * 16);
        const int itN    = it + G;
        const int itNc   = (itN < 12500) ? itN : 0;
        const int ebaseN = __builtin_amdgcn_readfirstlane(itNc * 64 + wave * 16);

        // ---- convert A(cur) -> bf16 hi/lo
        short8 ah[2], al[2];
#pragma unroll
        for (int p = 0; p < 2; ++p) {
            const float xv[8] = {arC[2*p].x, arC[2*p].y, arC[2*p].z, arC[2*p].w,
                                 arC[2*p+1].x, arC[2*p+1].y, arC[2*p+1].z, arC[2*p+1].w};
#pragma unroll
            for (int j = 0; j < 8; ++j) {
                const short hb = f2bf(xv[j]);
                ah[p][j] = hb;
                al[p][j] = f2bf(xv[j] - bf2f(hb));
            }
        }

        // ---- next-iteration index scalar loads
#pragma unroll
        for (int r = 0; r < 16; ++r) {
            seN[r] = src_idx[ebaseN + r];
            deN[r] = dst_idx[ebaseN + r];
        }

        // ---- current-iteration gathers
        float vv[16], kv[16], qv[16];
#pragma unroll
        for (int r = 0; r < 16; ++r) vv[r] = Vn[seC[r] * 64 + lane];
#pragma unroll
        for (int r = 0; r < 16; ++r) {
            kv[r] = Kn[seC[r] * 64 + lane];
            qv[r] = Qn[deC[r] * 64 + lane];
        }

        // ---- A(next) raw loads
#pragma unroll
        for (int p = 0; p < 2; ++p) {
            const float* srcp = edge_attr + (size_t)(ebaseN + c4) * 64 + p * 32 + (g << 3);
            arN[2 * p]     = *(const float4*)srcp;
            arN[2 * p + 1] = *(const float4*)(srcp + 4);
        }

        // ---- MFMA (3-product bf16 split)
        f32x4 acc[8] = {};
        __builtin_amdgcn_s_setprio(1);
#pragma unroll
        for (int kh = 0; kh < 2; ++kh) {
#pragma unroll
            for (int ct = 0; ct < 8; ++ct) {
                const short8 bh = Bhi[(ct * 2 + kh) * 64 + lane];
                const short8 bl = Blo[(ct * 2 + kh) * 64 + lane];
                acc[ct] = __builtin_amdgcn_mfma_f32_16x16x32_bf16(ah[kh], bh, acc[ct], 0, 0, 0);
                acc[ct] = __builtin_amdgcn_mfma_f32_16x16x32_bf16(al[kh], bh, acc[ct], 0, 0, 0);
                acc[ct] = __builtin_amdgcn_mfma_f32_16x16x32_bf16(ah[kh], bl, acc[ct], 0, 0, 0);
            }
        }
        __builtin_amdgcn_s_setprio(0);

        // ---- score phase: 4 fenced quarters (R10-proven structure)
#pragma unroll
        for (int q = 0; q < 4; ++q) {
            if (g == q) {
#pragma unroll
                for (int ct = 0; ct < 8; ++ct) {
                    const int col = (ct << 4) + c4;
                    const float b = bEs[col];
                    f32x4 vq = acc[ct];
                    vq[0] += b; vq[1] += b; vq[2] += b; vq[3] += b;
                    *(f32x4*)(Ebuf_w + ((col + (col >> 3)) << 2)) = vq;
                }
            }
            __asm__ volatile("s_waitcnt lgkmcnt(0)" ::: "memory");
            __builtin_amdgcn_sched_barrier(0);
#pragma unroll
            for (int rr = 0; rr < 4; ++rr) {
                const int e = ebaseC + q * 4 + rr;
                const int d = deC[q * 4 + rr];
                const float kq = kv[q * 4 + rr] + qv[q * 4 + rr];
                const float ew = Ebuf_w[ewoff + rr];
                const float eb = Ebuf_w[eboff + rr];
                float sc = kq * ew;
                sc = copysignf(sqrtf(fabsf(sc)), sc) + eb;  // signed sqrt
                wE_out[(size_t)e * 64 + lane] = sc;

                float pp = sc * aw;
                pp += __shfl_xor(pp, 1);
                pp += __shfl_xor(pp, 2);
                pp += __shfl_xor(pp, 4);
                pp = fminf(fmaxf(pp, -CLAMP_V), CLAMP_V);
                const float ex = __expf(pp);
                if (kk == 0) unsafeAtomicAdd(&denom[d * 8 + h], ex);

                if (FOLD_VE) {
                    // rowV layout == sc layout: zero shuffles
                    unsafeAtomicAdd(&wV_num[(size_t)d * 64 + lane], ex * vv[q * 4 + rr]);
                    unsafeAtomicAdd(&rowV_num[(size_t)d * 64 + lane], ex * sc);
                } else {
                    float rsum = 0.f;
#pragma unroll
                    for (int dd = 0; dd < 8; ++dd) {
                        const float etd = __shfl(sc, (lane & 56) + dd);
                        rsum += etd * veR[dd];
                    }
                    unsafeAtomicAdd(&wV_num[(size_t)d * 64 + lane],
                                    ex * (vv[q * 4 + rr] + rsum));
                }
            }
            __builtin_amdgcn_sched_barrier(0);
        }

        // ---- rotate pipeline state
#pragma unroll
        for (int p = 0; p < 4; ++p) arC[p] = arN[p];
#pragma unroll
        for (int r = 0; r < 16; ++r) { seC[r] = seN[r]; deC[r] = deN[r]; }
    }
}

// ---------------- Kernel 3: finalize ----------------
// FOLD_VE=1: wV = (wV_num + rowV_num @ VeRow) / denom   (reference order)
// FOLD_VE=0: wV = wV_num / denom
template<int FOLD_VE>
__global__ __launch_bounds__(256) void finalize_kernel(
    const float* __restrict__ denom, const float* __restrict__ rowV_num,
    const float* __restrict__ VeRow, float* __restrict__ wV)
{
    __shared__ float VeL[512];
    const int t = threadIdx.x;
    if (FOLD_VE) {
        for (int i = t; i < 512; i += 256) VeL[i] = VeRow[i];
        __syncthreads();
    }
    const int i = blockIdx.x * 256 + t;             // 12500 * 256 = 3.2M
    const int n = i >> 6;
    const int lane6 = i & 63;                       // h*8+kk
    const int h = lane6 >> 3;
    const float dn = denom[n * 8 + h] + 1e-16f;
    float num = wV[i];
    if (FOLD_VE) {
#pragma unroll
        for (int dd = 0; dd < 8; ++dd) {
            num += rowV_num[n * 64 + h * 8 + dd] * VeL[dd * 64 + lane6];
        }
    }
    wV[i] = num / dn;
}

extern "C" void kernel_launch(void* const* d_in, const int* in_sizes, int n_in,
                              void* d_out, int out_size, void* d_ws, size_t ws_size,
                              hipStream_t stream) {
    const float* x         = (const float*)d_in[0];
    const float* edge_attr = (const float*)d_in[1];
    const int*   ei        = (const int*)  d_in[2];
    const float* WQ = (const float*)d_in[3];
    const float* bQ = (const float*)d_in[4];
    const float* WK = (const float*)d_in[5];
    const float* bK = (const float*)d_in[6];
    const float* WE = (const float*)d_in[7];
    const float* bE = (const float*)d_in[8];
    const float* WV = (const float*)d_in[9];
    const float* bV = (const float*)d_in[10];
    const float* Aw = (const float*)d_in[11];
    const float* VeRow = (const float*)d_in[12];

    float* out    = (float*)d_out;
    float* wV_out = out;                        // 50000*64 (numerator, then final)
    float* wE_out = out + (size_t)N_NODES * 64; // 800000*64

    float* ws    = (float*)d_ws;
    float* Q     = ws;                          // 3.2M floats
    float* K     = ws + 3200000;
    float* V     = ws + 6400000;
    float* denom = ws + 9600000;                // 0.4M floats
    float* rowV  = ws + 10000000;               // 3.2M floats (needs 52.8MB total)

    const bool fold = (ws_size >= (size_t)13200000 * sizeof(float));

    const int* src_idx = ei;
    const int* dst_idx = ei + N_EDGES;

    hipMemsetAsync(wV_out, 0, (size_t)N_NODES * 64 * sizeof(float), stream);
    hipMemsetAsync(denom, 0, (size_t)N_NODES * 8 * sizeof(float), stream);
    if (fold) hipMemsetAsync(rowV, 0, (size_t)N_NODES * 64 * sizeof(float), stream);

    qkv_kernel<<<3125, 256, 0, stream>>>(x, WQ, bQ, WK, bK, WV, bV, Q, K, V);
    if (fold) {
        edge_kernel<1><<<768, 256, 0, stream>>>(edge_attr, src_idx, dst_idx, WE, bE, Aw,
                                                Q, K, V, VeRow, wE_out, denom, wV_out, rowV);
        finalize_kernel<1><<<12500, 256, 0, stream>>>(denom, rowV, VeRow, wV_out);
    } else {
        edge_kernel<0><<<768, 256, 0, stream>>>(edge_attr, src_idx, dst_idx, WE, bE, Aw,
                                                Q, K, V, VeRow, wE_out, denom, wV_out, rowV);
        finalize_kernel<0><<<12500, 256, 0, stream>>>(denom, rowV, VeRow, wV_out);
    }
}

// Round 15
// 320.239 us; speedup vs baseline: 1.5096x; 1.5096x over previous
//
#include <hip/hip_runtime.h>
#include <hip/hip_bf16.h>
#include <math.h>

#define N_NODES 50000
#define N_EDGES 800000
#define CLAMP_V 5.0f

typedef short short8 __attribute__((ext_vector_type(8)));
typedef float f32x4  __attribute__((ext_vector_type(4)));

static __device__ inline short f2bf(float x) {
    __hip_bfloat16 h = __float2bfloat16(x);   // RNE
    return __builtin_bit_cast(short, h);
}
static __device__ inline float bf2f(short s) {
    unsigned u = ((unsigned)(unsigned short)s) << 16;
    return __builtin_bit_cast(float, u);
}

// ---------------- Kernel 1: Q/K/V node projections (unchanged, proven) ----------------
__global__ __launch_bounds__(256) void qkv_kernel(
    const float* __restrict__ x,
    const float* __restrict__ WQ, const float* __restrict__ bQ,
    const float* __restrict__ WK, const float* __restrict__ bK,
    const float* __restrict__ WV, const float* __restrict__ bV,
    float* __restrict__ Q, float* __restrict__ K, float* __restrict__ V)
{
    const int t = threadIdx.x;
    const int c = t & 63;
    const int nl = t >> 6;
    const int base = blockIdx.x * 16;

    float accQ[4], accK[4], accV[4];
    int nodes[4];
#pragma unroll
    for (int j = 0; j < 4; ++j) {
        nodes[j] = base + j * 4 + nl;
        accQ[j] = bQ[c]; accK[j] = bK[c]; accV[j] = bV[c];
    }
    for (int k = 0; k < 64; ++k) {
        const float wq = WQ[k * 64 + c];
        const float wk = WK[k * 64 + c];
        const float wv = WV[k * 64 + c];
#pragma unroll
        for (int j = 0; j < 4; ++j) {
            const float xv = x[nodes[j] * 64 + k];
            accQ[j] += xv * wq;
            accK[j] += xv * wk;
            accV[j] += xv * wv;
        }
    }
#pragma unroll
    for (int j = 0; j < 4; ++j) {
        const int n = nodes[j];
        Q[n * 64 + c] = accQ[j];
        K[n * 64 + c] = accK[j];
        V[n * 64 + c] = accV[j];
    }
}

// ---------------- Kernel 2: fused E-GEMM + score + denom + numerator ----------------
// R10 skeleton (proven best) with the score phase switched from 4 fenced
// quarters (2KB buf) to 2 fenced halves (4KB buf, R2's proven layout).
// Rationale (R13 evidence): fence-scope reduction gave 1.5x per-wave speed
// at one-fence granularity; here we take 2-fence granularity while KEEPING
// 3 blocks/CU: LDS = 32768(B) + 16384(E^T) + 512(bEs) = 49664 < 53248.
// Identical arithmetic; identical fence mechanism (asm lgkmcnt + sched_barrier).
__global__ __launch_bounds__(256, 3) void edge_kernel(
    const float* __restrict__ edge_attr,
    const int* __restrict__ src_idx, const int* __restrict__ dst_idx,
    const float* __restrict__ WE, const float* __restrict__ bE,
    const float* __restrict__ Aw,
    const float* __restrict__ Qn, const float* __restrict__ Kn,
    const float* __restrict__ Vn, const float* __restrict__ VeRow,
    float* __restrict__ wE_out, float* __restrict__ denom,
    float* __restrict__ wV_num)
{
    // [0,16K)=B_hi  [16K,32K)=B_lo  [32K,48K)=E^T half-bufs (4KB/wave)
    __shared__ __align__(16) char raw[49152];
    __shared__ float bEs[128];

    short8* Bhi = (short8*)raw;                  // [(ct*2+kh)*64 + lane]
    short8* Blo = (short8*)(raw + 16384);

    const int t = threadIdx.x;
    const int wave = t >> 6;
    const int lane = t & 63;

    // ---- init: bf16 hi/lo B-fragments from global WE
    short* BhiE = (short*)raw;
    short* BloE = (short*)(raw + 16384);
    for (int i = t; i < 8192; i += 256) {
        const int j  = i & 7;
        const int ln = (i >> 3) & 63;
        const int kh = (i >> 9) & 1;
        const int ct = i >> 10;
        const int k   = kh * 32 + ((ln >> 4) << 3) + j;
        const int col = (ct << 4) + (ln & 15);
        const float w = WE[k * 128 + col];
        const short hb = f2bf(w);
        BhiE[i] = hb;
        BloE[i] = f2bf(w - bf2f(hb));
    }
    if (t < 128) bEs[t] = bE[t];
    __syncthreads();

    float* Ebuf_w = (float*)(raw + 32768 + wave * 4096);  // [col*8 + e8] (R2 layout)

    const int h    = lane >> 3;
    const int kk   = lane & 7;
    const int g    = lane >> 4;
    const int c4   = lane & 15;
    const int h16k = (h << 4) + kk;

    // loop-invariant weights in registers (global reads, once, L2-hot)
    const float aw = Aw[kk * 8 + h];
    float veR[8];
#pragma unroll
    for (int dd = 0; dd < 8; ++dd) veR[dd] = VeRow[dd * 64 + lane];

    const int G = (int)gridDim.x;

    // pipeline state: current A-raw + indices; next A-raw + indices
    float4 arC[4], arN[4];
    int seC[16], deC[16], seN[16], deN[16];

    // ---- prologue
    int it = blockIdx.x;
    {
        const int ebase0 = __builtin_amdgcn_readfirstlane(it * 64 + wave * 16);
#pragma unroll
        for (int p = 0; p < 2; ++p) {
            const float* srcp = edge_attr + (size_t)(ebase0 + c4) * 64 + p * 32 + (g << 3);
            arC[2 * p]     = *(const float4*)srcp;
            arC[2 * p + 1] = *(const float4*)(srcp + 4);
        }
#pragma unroll
        for (int r = 0; r < 16; ++r) {
            seC[r] = src_idx[ebase0 + r];
            deC[r] = dst_idx[ebase0 + r];
        }
    }

    for (; it < 12500; it += G) {
        const int ebaseC = __builtin_amdgcn_readfirstlane(it * 64 + wave * 16);
        const int itN    = it + G;
        const int itNc   = (itN < 12500) ? itN : 0;   // clamped (unused at tail)
        const int ebaseN = __builtin_amdgcn_readfirstlane(itNc * 64 + wave * 16);

        // ---- convert A(cur) -> bf16 hi/lo (arC landed long ago; no wait)
        short8 ah[2], al[2];
#pragma unroll
        for (int p = 0; p < 2; ++p) {
            const float xv[8] = {arC[2*p].x, arC[2*p].y, arC[2*p].z, arC[2*p].w,
                                 arC[2*p+1].x, arC[2*p+1].y, arC[2*p+1].z, arC[2*p+1].w};
#pragma unroll
            for (int j = 0; j < 8; ++j) {
                const short hb = f2bf(xv[j]);
                ah[p][j] = hb;
                al[p][j] = f2bf(xv[j] - bf2f(hb));
            }
        }

        // ---- next-iteration index scalar loads (land during MFMA)
#pragma unroll
        for (int r = 0; r < 16; ++r) {
            seN[r] = src_idx[ebaseN + r];
            deN[r] = dst_idx[ebaseN + r];
        }

        // ---- gathers for CURRENT iteration (consumed in score phase)
        float vv[16], kv[16], qv[16];
#pragma unroll
        for (int r = 0; r < 16; ++r) vv[r] = Vn[seC[r] * 64 + lane];
#pragma unroll
        for (int r = 0; r < 16; ++r) {
            kv[r] = Kn[seC[r] * 64 + lane];
            qv[r] = Qn[deC[r] * 64 + lane];
        }

        // ---- A(next) raw loads: issued last, consumed at body end
#pragma unroll
        for (int p = 0; p < 2; ++p) {
            const float* srcp = edge_attr + (size_t)(ebaseN + c4) * 64 + p * 32 + (g << 3);
            arN[2 * p]     = *(const float4*)srcp;
            arN[2 * p + 1] = *(const float4*)(srcp + 4);
        }

        // ---- MFMA (3-product bf16 split)
        f32x4 acc[8] = {};
        __builtin_amdgcn_s_setprio(1);
#pragma unroll
        for (int kh = 0; kh < 2; ++kh) {
#pragma unroll
            for (int ct = 0; ct < 8; ++ct) {
                const short8 bh = Bhi[(ct * 2 + kh) * 64 + lane];
                const short8 bl = Blo[(ct * 2 + kh) * 64 + lane];
                acc[ct] = __builtin_amdgcn_mfma_f32_16x16x32_bf16(ah[kh], bh, acc[ct], 0, 0, 0);
                acc[ct] = __builtin_amdgcn_mfma_f32_16x16x32_bf16(al[kh], bh, acc[ct], 0, 0, 0);
                acc[ct] = __builtin_amdgcn_mfma_f32_16x16x32_bf16(ah[kh], bl, acc[ct], 0, 0, 0);
            }
        }
        __builtin_amdgcn_s_setprio(0);

        // ---- score phase: 2 fenced halves (R2-proven layout + fence mechanism)
#pragma unroll
        for (int H = 0; H < 2; ++H) {
            if ((g >> 1) == H) {
                // lanes owning this half's 8 edges write E^T: rows (g&1)*4+rr
#pragma unroll
                for (int ct = 0; ct < 8; ++ct) {
                    const int col = (ct << 4) + c4;
                    const float b = bEs[col];
                    f32x4 vq = acc[ct];
                    vq[0] += b; vq[1] += b; vq[2] += b; vq[3] += b;
                    *(f32x4*)(Ebuf_w + col * 8 + (g & 1) * 4) = vq;
                }
            }
            __asm__ volatile("s_waitcnt lgkmcnt(0)" ::: "memory");
            __builtin_amdgcn_sched_barrier(0);
            // 8 independent edge chains — scheduler free to interleave
#pragma unroll
            for (int j = 0; j < 8; ++j) {
                const int idx = H * 8 + j;
                const int e = ebaseC + idx;
                const int d = deC[idx];
                const float kq = kv[idx] + qv[idx];
                const float ew = Ebuf_w[h16k * 8 + j];
                const float eb = Ebuf_w[(h16k + 8) * 8 + j];
                float sc = kq * ew;
                sc = copysignf(sqrtf(fabsf(sc)), sc) + eb;  // signed sqrt
                wE_out[(size_t)e * 64 + lane] = sc;

                float pp = sc * aw;
                pp += __shfl_xor(pp, 1);
                pp += __shfl_xor(pp, 2);
                pp += __shfl_xor(pp, 4);
                pp = fminf(fmaxf(pp, -CLAMP_V), CLAMP_V);
                const float ex = __expf(pp);
                if (kk == 0) unsafeAtomicAdd(&denom[d * 8 + h], ex);

                float rsum = 0.f;
#pragma unroll
                for (int dd = 0; dd < 8; ++dd) {
                    const float etd = __shfl(sc, (lane & 56) + dd);  // e_t[h,dd]
                    rsum += etd * veR[dd];                           // VeRow[dd,h,kk]
                }
                unsafeAtomicAdd(&wV_num[(size_t)d * 64 + lane],
                                ex * (vv[idx] + rsum));
            }
            __builtin_amdgcn_sched_barrier(0);   // next half's writes stay below
        }

        // ---- rotate pipeline state (arN landed during MFMA+score)
#pragma unroll
        for (int p = 0; p < 4; ++p) arC[p] = arN[p];
#pragma unroll
        for (int r = 0; r < 16; ++r) { seC[r] = seN[r]; deC[r] = deN[r]; }
    }
}

// ---------------- Kernel 3: finalize — wV = numer / denom ----------------
__global__ __launch_bounds__(256) void finalize_kernel(
    const float* __restrict__ denom, float* __restrict__ wV)
{
    const int i = blockIdx.x * 256 + threadIdx.x;   // 12500 * 256 = 3.2M
    const int n = i >> 6;
    const int h = (i >> 3) & 7;
    const float dn = denom[n * 8 + h] + 1e-16f;
    wV[i] = wV[i] / dn;
}

extern "C" void kernel_launch(void* const* d_in, const int* in_sizes, int n_in,
                              void* d_out, int out_size, void* d_ws, size_t ws_size,
                              hipStream_t stream) {
    const float* x         = (const float*)d_in[0];
    const float* edge_attr = (const float*)d_in[1];
    const int*   ei        = (const int*)  d_in[2];
    const float* WQ = (const float*)d_in[3];
    const float* bQ = (const float*)d_in[4];
    const float* WK = (const float*)d_in[5];
    const float* bK = (const float*)d_in[6];
    const float* WE = (const float*)d_in[7];
    const float* bE = (const float*)d_in[8];
    const float* WV = (const float*)d_in[9];
    const float* bV = (const float*)d_in[10];
    const float* Aw = (const float*)d_in[11];
    const float* VeRow = (const float*)d_in[12];

    float* out    = (float*)d_out;
    float* wV_out = out;                        // 50000*64 (numerator, then final)
    float* wE_out = out + (size_t)N_NODES * 64; // 800000*64

    float* ws    = (float*)d_ws;
    float* Q     = ws;
    float* K     = ws + 3200000;
    float* V     = ws + 6400000;
    float* denom = ws + 9600000;

    const int* src_idx = ei;
    const int* dst_idx = ei + N_EDGES;

    hipMemsetAsync(wV_out, 0, (size_t)N_NODES * 64 * sizeof(float), stream);
    hipMemsetAsync(denom, 0, (size_t)N_NODES * 8 * sizeof(float), stream);

    qkv_kernel<<<3125, 256, 0, stream>>>(x, WQ, bQ, WK, bK, WV, bV, Q, K, V);
    edge_kernel<<<768, 256, 0, stream>>>(edge_attr, src_idx, dst_idx, WE, bE, Aw,
                                         Q, K, V, VeRow, wE_out, denom, wV_out);
    finalize_kernel<<<12500, 256, 0, stream>>>(denom, wV_out);
}

// Round 16
// 320.133 us; speedup vs baseline: 1.5101x; 1.0003x over previous
//
#include <hip/hip_runtime.h>
#include <hip/hip_bf16.h>
#include <math.h>

#define N_NODES 50000
#define N_EDGES 800000
#define CLAMP_V 5.0f

typedef short short8 __attribute__((ext_vector_type(8)));
typedef float f32x4  __attribute__((ext_vector_type(4)));

static __device__ inline short f2bf(float x) {
    __hip_bfloat16 h = __float2bfloat16(x);   // RNE
    return __builtin_bit_cast(short, h);
}
static __device__ inline float bf2f(short s) {
    unsigned u = ((unsigned)(unsigned short)s) << 16;
    return __builtin_bit_cast(float, u);
}

// ---------------- Kernel 1: Q/K/V node projections (unchanged, proven) ----------------
__global__ __launch_bounds__(256) void qkv_kernel(
    const float* __restrict__ x,
    const float* __restrict__ WQ, const float* __restrict__ bQ,
    const float* __restrict__ WK, const float* __restrict__ bK,
    const float* __restrict__ WV, const float* __restrict__ bV,
    float* __restrict__ Q, float* __restrict__ K, float* __restrict__ V)
{
    const int t = threadIdx.x;
    const int c = t & 63;
    const int nl = t >> 6;
    const int base = blockIdx.x * 16;

    float accQ[4], accK[4], accV[4];
    int nodes[4];
#pragma unroll
    for (int j = 0; j < 4; ++j) {
        nodes[j] = base + j * 4 + nl;
        accQ[j] = bQ[c]; accK[j] = bK[c]; accV[j] = bV[c];
    }
    for (int k = 0; k < 64; ++k) {
        const float wq = WQ[k * 64 + c];
        const float wk = WK[k * 64 + c];
        const float wv = WV[k * 64 + c];
#pragma unroll
        for (int j = 0; j < 4; ++j) {
            const float xv = x[nodes[j] * 64 + k];
            accQ[j] += xv * wq;
            accK[j] += xv * wk;
            accV[j] += xv * wv;
        }
    }
#pragma unroll
    for (int j = 0; j < 4; ++j) {
        const int n = nodes[j];
        Q[n * 64 + c] = accQ[j];
        K[n * 64 + c] = accK[j];
        V[n * 64 + c] = accV[j];
    }
}

// ---------------- Kernel 2: fused E-GEMM + score + denom + numerator ----------------
// R15 base (2 fenced halves, proven 255us) with two DS-chain cuts:
//  (a) Ebuf padded per 16 cols: word = (col + col>>4)*8 + e8. R15's [col*8]
//      read was 8-way bank-conflicted (bank independent of h); padded banks
//      are distinct mod 4 across h -> 2-way (free). 4352 B/wave,
//      LDS = 32768 + 4*4352 + 512 = 50688 < 53248 -> still 3 blocks/CU.
//  (b) logit via the rsum broadcasts: pp = sum_dd etd*Aw[dd*8+h] (8 FMAs,
//      awR registers) — deletes the 3-shfl serial reduce chain per edge.
//      Summation order within 8 changes (tree->linear): logit delta ~1e-7.
__global__ __launch_bounds__(256, 3) void edge_kernel(
    const float* __restrict__ edge_attr,
    const int* __restrict__ src_idx, const int* __restrict__ dst_idx,
    const float* __restrict__ WE, const float* __restrict__ bE,
    const float* __restrict__ Aw,
    const float* __restrict__ Qn, const float* __restrict__ Kn,
    const float* __restrict__ Vn, const float* __restrict__ VeRow,
    float* __restrict__ wE_out, float* __restrict__ denom,
    float* __restrict__ wV_num)
{
    // [0,16K)=B_hi  [16K,32K)=B_lo  [32K, +4*4352)=E^T half-bufs (padded)
    __shared__ __align__(16) char raw[50176];
    __shared__ float bEs[128];

    short8* Bhi = (short8*)raw;                  // [(ct*2+kh)*64 + lane]
    short8* Blo = (short8*)(raw + 16384);

    const int t = threadIdx.x;
    const int wave = t >> 6;
    const int lane = t & 63;

    // ---- init: bf16 hi/lo B-fragments from global WE
    short* BhiE = (short*)raw;
    short* BloE = (short*)(raw + 16384);
    for (int i = t; i < 8192; i += 256) {
        const int j  = i & 7;
        const int ln = (i >> 3) & 63;
        const int kh = (i >> 9) & 1;
        const int ct = i >> 10;
        const int k   = kh * 32 + ((ln >> 4) << 3) + j;
        const int col = (ct << 4) + (ln & 15);
        const float w = WE[k * 128 + col];
        const short hb = f2bf(w);
        BhiE[i] = hb;
        BloE[i] = f2bf(w - bf2f(hb));
    }
    if (t < 128) bEs[t] = bE[t];
    __syncthreads();

    float* Ebuf_w = (float*)(raw + 32768 + wave * 4352);  // [(col+col>>4)*8 + e8]

    const int h    = lane >> 3;
    const int kk   = lane & 7;
    const int g    = lane >> 4;
    const int c4   = lane & 15;
    const int h16k = (h << 4) + kk;
    const int ewoff = (h16k + h) << 3;            // (col1 + col1>>4)*8, col1=h16k
    const int eboff = (h16k + 8 + h) << 3;        // col2 = h16k+8 (same >>4 = h)

    // loop-invariant weights in registers (global reads, once, L2-hot)
    float veR[8], awR[8];
#pragma unroll
    for (int dd = 0; dd < 8; ++dd) {
        veR[dd] = VeRow[dd * 64 + lane];
        awR[dd] = Aw[dd * 8 + h];
    }

    const int G = (int)gridDim.x;

    // pipeline state: current A-raw + indices; next A-raw + indices
    float4 arC[4], arN[4];
    int seC[16], deC[16], seN[16], deN[16];

    // ---- prologue
    int it = blockIdx.x;
    {
        const int ebase0 = __builtin_amdgcn_readfirstlane(it * 64 + wave * 16);
#pragma unroll
        for (int p = 0; p < 2; ++p) {
            const float* srcp = edge_attr + (size_t)(ebase0 + c4) * 64 + p * 32 + (g << 3);
            arC[2 * p]     = *(const float4*)srcp;
            arC[2 * p + 1] = *(const float4*)(srcp + 4);
        }
#pragma unroll
        for (int r = 0; r < 16; ++r) {
            seC[r] = src_idx[ebase0 + r];
            deC[r] = dst_idx[ebase0 + r];
        }
    }

    for (; it < 12500; it += G) {
        const int ebaseC = __builtin_amdgcn_readfirstlane(it * 64 + wave * 16);
        const int itN    = it + G;
        const int itNc   = (itN < 12500) ? itN : 0;   // clamped (unused at tail)
        const int ebaseN = __builtin_amdgcn_readfirstlane(itNc * 64 + wave * 16);

        // ---- convert A(cur) -> bf16 hi/lo (arC landed long ago; no wait)
        short8 ah[2], al[2];
#pragma unroll
        for (int p = 0; p < 2; ++p) {
            const float xv[8] = {arC[2*p].x, arC[2*p].y, arC[2*p].z, arC[2*p].w,
                                 arC[2*p+1].x, arC[2*p+1].y, arC[2*p+1].z, arC[2*p+1].w};
#pragma unroll
            for (int j = 0; j < 8; ++j) {
                const short hb = f2bf(xv[j]);
                ah[p][j] = hb;
                al[p][j] = f2bf(xv[j] - bf2f(hb));
            }
        }

        // ---- next-iteration index scalar loads (land during MFMA)
#pragma unroll
        for (int r = 0; r < 16; ++r) {
            seN[r] = src_idx[ebaseN + r];
            deN[r] = dst_idx[ebaseN + r];
        }

        // ---- gathers for CURRENT iteration (consumed in score phase)
        float vv[16], kv[16], qv[16];
#pragma unroll
        for (int r = 0; r < 16; ++r) vv[r] = Vn[seC[r] * 64 + lane];
#pragma unroll
        for (int r = 0; r < 16; ++r) {
            kv[r] = Kn[seC[r] * 64 + lane];
            qv[r] = Qn[deC[r] * 64 + lane];
        }

        // ---- A(next) raw loads: issued last, consumed at body end
#pragma unroll
        for (int p = 0; p < 2; ++p) {
            const float* srcp = edge_attr + (size_t)(ebaseN + c4) * 64 + p * 32 + (g << 3);
            arN[2 * p]     = *(const float4*)srcp;
            arN[2 * p + 1] = *(const float4*)(srcp + 4);
        }

        // ---- MFMA (3-product bf16 split)
        f32x4 acc[8] = {};
        __builtin_amdgcn_s_setprio(1);
#pragma unroll
        for (int kh = 0; kh < 2; ++kh) {
#pragma unroll
            for (int ct = 0; ct < 8; ++ct) {
                const short8 bh = Bhi[(ct * 2 + kh) * 64 + lane];
                const short8 bl = Blo[(ct * 2 + kh) * 64 + lane];
                acc[ct] = __builtin_amdgcn_mfma_f32_16x16x32_bf16(ah[kh], bh, acc[ct], 0, 0, 0);
                acc[ct] = __builtin_amdgcn_mfma_f32_16x16x32_bf16(al[kh], bh, acc[ct], 0, 0, 0);
                acc[ct] = __builtin_amdgcn_mfma_f32_16x16x32_bf16(ah[kh], bl, acc[ct], 0, 0, 0);
            }
        }
        __builtin_amdgcn_s_setprio(0);

        // ---- score phase: 2 fenced halves (padded E^T layout)
#pragma unroll
        for (int H = 0; H < 2; ++H) {
            if ((g >> 1) == H) {
                // lanes owning this half's 8 edges write E^T: rows (g&1)*4+rr
#pragma unroll
                for (int ct = 0; ct < 8; ++ct) {
                    const int col = (ct << 4) + c4;
                    const float b = bEs[col];
                    f32x4 vq = acc[ct];
                    vq[0] += b; vq[1] += b; vq[2] += b; vq[3] += b;
                    *(f32x4*)(Ebuf_w + ((col + ct) << 3) + (g & 1) * 4) = vq;
                }
            }
            __asm__ volatile("s_waitcnt lgkmcnt(0)" ::: "memory");
            __builtin_amdgcn_sched_barrier(0);
            // 8 independent edge chains — scheduler free to interleave
#pragma unroll
            for (int j = 0; j < 8; ++j) {
                const int idx = H * 8 + j;
                const int e = ebaseC + idx;
                const int d = deC[idx];
                const float kq = kv[idx] + qv[idx];
                const float ew = Ebuf_w[ewoff + j];
                const float eb = Ebuf_w[eboff + j];
                float sc = kq * ew;
                sc = copysignf(sqrtf(fabsf(sc)), sc) + eb;  // signed sqrt
                wE_out[(size_t)e * 64 + lane] = sc;

                // broadcast e_t[h,dd] once; feed BOTH rsum and the logit
                float rsum = 0.f, pp = 0.f;
#pragma unroll
                for (int dd = 0; dd < 8; ++dd) {
                    const float etd = __shfl(sc, (lane & 56) + dd);  // e_t[h,dd]
                    rsum += etd * veR[dd];                           // VeRow[dd,h,kk]
                    pp   += etd * awR[dd];                           // Aw[dd,h]
                }
                pp = fminf(fmaxf(pp, -CLAMP_V), CLAMP_V);
                const float ex = __expf(pp);
                if (kk == 0) unsafeAtomicAdd(&denom[d * 8 + h], ex);
                unsafeAtomicAdd(&wV_num[(size_t)d * 64 + lane],
                                ex * (vv[idx] + rsum));
            }
            __builtin_amdgcn_sched_barrier(0);   // next half's writes stay below
        }

        // ---- rotate pipeline state (arN landed during MFMA+score)
#pragma unroll
        for (int p = 0; p < 4; ++p) arC[p] = arN[p];
#pragma unroll
        for (int r = 0; r < 16; ++r) { seC[r] = seN[r]; deC[r] = deN[r]; }
    }
}

// ---------------- Kernel 3: finalize — wV = numer / denom ----------------
__global__ __launch_bounds__(256) void finalize_kernel(
    const float* __restrict__ denom, float* __restrict__ wV)
{
    const int i = blockIdx.x * 256 + threadIdx.x;   // 12500 * 256 = 3.2M
    const int n = i >> 6;
    const int h = (i >> 3) & 7;
    const float dn = denom[n * 8 + h] + 1e-16f;
    wV[i] = wV[i] / dn;
}

extern "C" void kernel_launch(void* const* d_in, const int* in_sizes, int n_in,
                              void* d_out, int out_size, void* d_ws, size_t ws_size,
                              hipStream_t stream) {
    const float* x         = (const float*)d_in[0];
    const float* edge_attr = (const float*)d_in[1];
    const int*   ei        = (const int*)  d_in[2];
    const float* WQ = (const float*)d_in[3];
    const float* bQ = (const float*)d_in[4];
    const float* WK = (const float*)d_in[5];
    const float* bK = (const float*)d_in[6];
    const float* WE = (const float*)d_in[7];
    const float* bE = (const float*)d_in[8];
    const float* WV = (const float*)d_in[9];
    const float* bV = (const float*)d_in[10];
    const float* Aw = (const float*)d_in[11];
    const float* VeRow = (const float*)d_in[12];

    float* out    = (float*)d_out;
    float* wV_out = out;                        // 50000*64 (numerator, then final)
    float* wE_out = out + (size_t)N_NODES * 64; // 800000*64

    float* ws    = (float*)d_ws;
    float* Q     = ws;
    float* K     = ws + 3200000;
    float* V     = ws + 6400000;
    float* denom = ws + 9600000;

    const int* src_idx = ei;
    const int* dst_idx = ei + N_EDGES;

    hipMemsetAsync(wV_out, 0, (size_t)N_NODES * 64 * sizeof(float), stream);
    hipMemsetAsync(denom, 0, (size_t)N_NODES * 8 * sizeof(float), stream);

    qkv_kernel<<<3125, 256, 0, stream>>>(x, WQ, bQ, WK, bK, WV, bV, Q, K, V);
    edge_kernel<<<768, 256, 0, stream>>>(edge_attr, src_idx, dst_idx, WE, bE, Aw,
                                         Q, K, V, VeRow, wE_out, denom, wV_out);
    finalize_kernel<<<12500, 256, 0, stream>>>(denom, wV_out);
}

// Round 18
// 319.111 us; speedup vs baseline: 1.5149x; 1.0032x over previous
//
#include <hip/hip_runtime.h>
#include <hip/hip_bf16.h>
#include <math.h>

#define N_NODES 50000
#define N_EDGES 800000
#define CLAMP_V 5.0f

typedef short short8 __attribute__((ext_vector_type(8)));
typedef short short4v __attribute__((ext_vector_type(4)));
typedef float f32x4  __attribute__((ext_vector_type(4)));

static __device__ inline short f2bf(float x) {
    __hip_bfloat16 h = __float2bfloat16(x);   // RNE
    return __builtin_bit_cast(short, h);
}
static __device__ inline float bf2f(short s) {
    unsigned u = ((unsigned)(unsigned short)s) << 16;
    return __builtin_bit_cast(float, u);
}

// ---------------- Kernel 1: Q/K/V node projections (unchanged, proven) ----------------
__global__ __launch_bounds__(256) void qkv_kernel(
    const float* __restrict__ x,
    const float* __restrict__ WQ, const float* __restrict__ bQ,
    const float* __restrict__ WK, const float* __restrict__ bK,
    const float* __restrict__ WV, const float* __restrict__ bV,
    float* __restrict__ Q, float* __restrict__ K, float* __restrict__ V)
{
    const int t = threadIdx.x;
    const int c = t & 63;
    const int nl = t >> 6;
    const int base = blockIdx.x * 16;

    float accQ[4], accK[4], accV[4];
    int nodes[4];
#pragma unroll
    for (int j = 0; j < 4; ++j) {
        nodes[j] = base + j * 4 + nl;
        accQ[j] = bQ[c]; accK[j] = bK[c]; accV[j] = bV[c];
    }
    for (int k = 0; k < 64; ++k) {
        const float wq = WQ[k * 64 + c];
        const float wk = WK[k * 64 + c];
        const float wv = WV[k * 64 + c];
#pragma unroll
        for (int j = 0; j < 4; ++j) {
            const float xv = x[nodes[j] * 64 + k];
            accQ[j] += xv * wq;
            accK[j] += xv * wk;
            accV[j] += xv * wv;
        }
    }
#pragma unroll
    for (int j = 0; j < 4; ++j) {
        const int n = nodes[j];
        Q[n * 64 + c] = accQ[j];
        K[n * 64 + c] = accK[j];
        V[n * 64 + c] = accV[j];
    }
}

// ---------------- Kernel 2: fused E-GEMM + score + denom + numerator ----------------
// ONE-FENCE schedule at 3 blocks/CU with FULL 3-product precision:
//  - E^T buffer stored as bf16 (rel err 2^-9 — RELATIVE errors pass through
//    the signed-sqrt safely, unlike R17's absolute 2-product error).
//  - Layout: addr_short = (col<<4) + ((col>>4)<<2) + idx. Writes: 8 packed
//    ds_write_b64/lane (8B-aligned); reads: bank spread by the (col>>4)
//    term -> ~2-way. 4160 B/wave.
//  - LDS = 32768(B hi+lo) + 4*4160(E^T) + 512(bEs) = 49920 -> 3 blocks/CU
//    with 4.7KB margin (no exact-fit cliff).
//  - Score: ONE lgkmcnt fence, then 16 independent edge chains (R13's
//    schedule — 1.5x per-wave rate — now at R10's occupancy).
__global__ __launch_bounds__(256, 3) void edge_kernel(
    const float* __restrict__ edge_attr,
    const int* __restrict__ src_idx, const int* __restrict__ dst_idx,
    const float* __restrict__ WE, const float* __restrict__ bE,
    const float* __restrict__ Aw,
    const float* __restrict__ Qn, const float* __restrict__ Kn,
    const float* __restrict__ Vn, const float* __restrict__ VeRow,
    float* __restrict__ wE_out, float* __restrict__ denom,
    float* __restrict__ wV_num)
{
    // [0,16K)=B_hi  [16K,32K)=B_lo  [32K, +4*4160)=E^T bf16 bufs
    __shared__ __align__(16) char raw[49408];
    __shared__ float bEs[128];

    short8* Bhi = (short8*)raw;                  // [(ct*2+kh)*64 + lane]
    short8* Blo = (short8*)(raw + 16384);

    const int t = threadIdx.x;
    const int wave = t >> 6;
    const int lane = t & 63;

    // ---- init: bf16 hi/lo B-fragments from global WE
    short* BhiE = (short*)raw;
    short* BloE = (short*)(raw + 16384);
    for (int i = t; i < 8192; i += 256) {
        const int j  = i & 7;
        const int ln = (i >> 3) & 63;
        const int kh = (i >> 9) & 1;
        const int ct = i >> 10;
        const int k   = kh * 32 + ((ln >> 4) << 3) + j;
        const int col = (ct << 4) + (ln & 15);
        const float w = WE[k * 128 + col];
        const short hb = f2bf(w);
        BhiE[i] = hb;
        BloE[i] = f2bf(w - bf2f(hb));
    }
    if (t < 128) bEs[t] = bE[t];
    __syncthreads();

    unsigned short* Eb = (unsigned short*)(raw + 32768 + wave * 4160);

    const int h    = lane >> 3;
    const int kk   = lane & 7;
    const int g    = lane >> 4;
    const int c4   = lane & 15;
    const int h16k = (h << 4) + kk;
    const int ewbase = (h16k << 4) + (h << 2);          // col1 = h16k, col1>>4 = h
    const int ebbase = ((h16k + 8) << 4) + (h << 2);    // col2 = h16k+8, col2>>4 = h

    // loop-invariant weights in registers (global reads, once, L2-hot)
    float veR[8], awR[8];
#pragma unroll
    for (int dd = 0; dd < 8; ++dd) {
        veR[dd] = VeRow[dd * 64 + lane];
        awR[dd] = Aw[dd * 8 + h];
    }

    const int G = (int)gridDim.x;

    // pipeline state: current A-raw + indices; next A-raw + indices
    float4 arC[4], arN[4];
    int seC[16], deC[16], seN[16], deN[16];

    // ---- prologue
    int it = blockIdx.x;
    {
        const int ebase0 = __builtin_amdgcn_readfirstlane(it * 64 + wave * 16);
#pragma unroll
        for (int p = 0; p < 2; ++p) {
            const float* srcp = edge_attr + (size_t)(ebase0 + c4) * 64 + p * 32 + (g << 3);
            arC[2 * p]     = *(const float4*)srcp;
            arC[2 * p + 1] = *(const float4*)(srcp + 4);
        }
#pragma unroll
        for (int r = 0; r < 16; ++r) {
            seC[r] = src_idx[ebase0 + r];
            deC[r] = dst_idx[ebase0 + r];
        }
    }

    for (; it < 12500; it += G) {
        const int ebaseC = __builtin_amdgcn_readfirstlane(it * 64 + wave * 16);
        const int itN    = it + G;
        const int itNc   = (itN < 12500) ? itN : 0;   // clamped (unused at tail)
        const int ebaseN = __builtin_amdgcn_readfirstlane(itNc * 64 + wave * 16);

        // ---- convert A(cur) -> bf16 hi/lo (arC landed long ago; no wait)
        short8 ah[2], al[2];
#pragma unroll
        for (int p = 0; p < 2; ++p) {
            const float xv[8] = {arC[2*p].x, arC[2*p].y, arC[2*p].z, arC[2*p].w,
                                 arC[2*p+1].x, arC[2*p+1].y, arC[2*p+1].z, arC[2*p+1].w};
#pragma unroll
            for (int j = 0; j < 8; ++j) {
                const short hb = f2bf(xv[j]);
                ah[p][j] = hb;
                al[p][j] = f2bf(xv[j] - bf2f(hb));
            }
        }

        // ---- next-iteration index scalar loads (land during MFMA)
#pragma unroll
        for (int r = 0; r < 16; ++r) {
            seN[r] = src_idx[ebaseN + r];
            deN[r] = dst_idx[ebaseN + r];
        }

        // ---- gathers for CURRENT iteration (consumed in score phase)
        float vv[16], kv[16], qv[16];
#pragma unroll
        for (int r = 0; r < 16; ++r) vv[r] = Vn[seC[r] * 64 + lane];
#pragma unroll
        for (int r = 0; r < 16; ++r) {
            kv[r] = Kn[seC[r] * 64 + lane];
            qv[r] = Qn[deC[r] * 64 + lane];
        }

        // ---- A(next) raw loads: issued last, consumed at body end
#pragma unroll
        for (int p = 0; p < 2; ++p) {
            const float* srcp = edge_attr + (size_t)(ebaseN + c4) * 64 + p * 32 + (g << 3);
            arN[2 * p]     = *(const float4*)srcp;
            arN[2 * p + 1] = *(const float4*)(srcp + 4);
        }

        // ---- MFMA (3-product bf16 split — full precision)
        f32x4 acc[8] = {};
        __builtin_amdgcn_s_setprio(1);
#pragma unroll
        for (int kh = 0; kh < 2; ++kh) {
#pragma unroll
            for (int ct = 0; ct < 8; ++ct) {
                const short8 bh = Bhi[(ct * 2 + kh) * 64 + lane];
                const short8 bl = Blo[(ct * 2 + kh) * 64 + lane];
                acc[ct] = __builtin_amdgcn_mfma_f32_16x16x32_bf16(ah[kh], bh, acc[ct], 0, 0, 0);
                acc[ct] = __builtin_amdgcn_mfma_f32_16x16x32_bf16(al[kh], bh, acc[ct], 0, 0, 0);
                acc[ct] = __builtin_amdgcn_mfma_f32_16x16x32_bf16(ah[kh], bl, acc[ct], 0, 0, 0);
            }
        }
        __builtin_amdgcn_s_setprio(0);

        // ---- E^T write: ALL lanes, bf16 packed b64, then ONE fence
        // lane (g,c4): rows 4g+0..3, cols 16ct+c4 -> shorts (col<<4)+(ct<<2)+4g
#pragma unroll
        for (int ct = 0; ct < 8; ++ct) {
            const int col = (ct << 4) + c4;
            const float b = bEs[col];
            short4v pk;
#pragma unroll
            for (int rr = 0; rr < 4; ++rr) pk[rr] = f2bf(acc[ct][rr] + b);
            *(short4v*)(Eb + (col << 4) + (ct << 2) + (g << 2)) = pk;
        }
        __asm__ volatile("s_waitcnt lgkmcnt(0)" ::: "memory");
        __builtin_amdgcn_sched_barrier(0);

        // ---- score: 16 independent edge chains (no intervening fences)
#pragma unroll
        for (int idx = 0; idx < 16; ++idx) {
            const int e = ebaseC + idx;
            const int d = deC[idx];
            const float kq = kv[idx] + qv[idx];
            const float ew = bf2f((short)Eb[ewbase + idx]);
            const float eb = bf2f((short)Eb[ebbase + idx]);
            float sc = kq * ew;
            sc = copysignf(sqrtf(fabsf(sc)), sc) + eb;  // signed sqrt
            wE_out[(size_t)e * 64 + lane] = sc;

            // broadcast e_t[h,dd] once; feed BOTH rsum and the logit
            float rsum = 0.f, pp = 0.f;
#pragma unroll
            for (int dd = 0; dd < 8; ++dd) {
                const float etd = __shfl(sc, (lane & 56) + dd);  // e_t[h,dd]
                rsum += etd * veR[dd];                           // VeRow[dd,h,kk]
                pp   += etd * awR[dd];                           // Aw[dd,h]
            }
            pp = fminf(fmaxf(pp, -CLAMP_V), CLAMP_V);
            const float ex = __expf(pp);
            if (kk == 0) unsafeAtomicAdd(&denom[d * 8 + h], ex);
            unsafeAtomicAdd(&wV_num[(size_t)d * 64 + lane],
                            ex * (vv[idx] + rsum));
        }
        __builtin_amdgcn_sched_barrier(0);   // next iter's E^T writes stay below

        // ---- rotate pipeline state (arN landed during MFMA+score)
#pragma unroll
        for (int p = 0; p < 4; ++p) arC[p] = arN[p];
#pragma unroll
        for (int r = 0; r < 16; ++r) { seC[r] = seN[r]; deC[r] = deN[r]; }
    }
}

// ---------------- Kernel 3: finalize — wV = numer / denom ----------------
__global__ __launch_bounds__(256) void finalize_kernel(
    const float* __restrict__ denom, float* __restrict__ wV)
{
    const int i = blockIdx.x * 256 + threadIdx.x;   // 12500 * 256 = 3.2M
    const int n = i >> 6;
    const int h = (i >> 3) & 7;
    const float dn = denom[n * 8 + h] + 1e-16f;
    wV[i] = wV[i] / dn;
}

extern "C" void kernel_launch(void* const* d_in, const int* in_sizes, int n_in,
                              void* d_out, int out_size, void* d_ws, size_t ws_size,
                              hipStream_t stream) {
    const float* x         = (const float*)d_in[0];
    const float* edge_attr = (const float*)d_in[1];
    const int*   ei        = (const int*)  d_in[2];
    const float* WQ = (const float*)d_in[3];
    const float* bQ = (const float*)d_in[4];
    const float* WK = (const float*)d_in[5];
    const float* bK = (const float*)d_in[6];
    const float* WE = (const float*)d_in[7];
    const float* bE = (const float*)d_in[8];
    const float* WV = (const float*)d_in[9];
    const float* bV = (const float*)d_in[10];
    const float* Aw = (const float*)d_in[11];
    const float* VeRow = (const float*)d_in[12];

    float* out    = (float*)d_out;
    float* wV_out = out;                        // 50000*64 (numerator, then final)
    float* wE_out = out + (size_t)N_NODES * 64; // 800000*64

    float* ws    = (float*)d_ws;
    float* Q     = ws;
    float* K     = ws + 3200000;
    float* V     = ws + 6400000;
    float* denom = ws + 9600000;

    const int* src_idx = ei;
    const int* dst_idx = ei + N_EDGES;

    hipMemsetAsync(wV_out, 0, (size_t)N_NODES * 64 * sizeof(float), stream);
    hipMemsetAsync(denom, 0, (size_t)N_NODES * 8 * sizeof(float), stream);

    qkv_kernel<<<3125, 256, 0, stream>>>(x, WQ, bQ, WK, bK, WV, bV, Q, K, V);
    edge_kernel<<<768, 256, 0, stream>>>(edge_attr, src_idx, dst_idx, WE, bE, Aw,
                                         Q, K, V, VeRow, wE_out, denom, wV_out);
    finalize_kernel<<<12500, 256, 0, stream>>>(denom, wV_out);
}